// Round 1
// baseline (181.501 us; speedup 1.0000x reference)
//
#include <hip/hip_runtime.h>
#include <hip/hip_bf16.h>

#define NN 50000
#define NE 625000
#define DIM 128

#define NBKT 782     // ceil(50000/64) buckets of 64 src nodes
#define NBKTP 784    // padded to multiple of 4
#define CAP 1536     // per-bucket capacity (mean 800, sd ~28)
#define CHUNK 4096   // edges per bin block (153 bin blocks)
#define NCHUNK ((NE + CHUNK - 1) / CHUNK)  // 153

// mega_setup grid partition: bin FIRST (long blocks overlap xcast stream)
#define XCAST_NB 6250              // NN*DIM/4/256
#define PREP_NB 65                 // (DIM*DIM+DIM+255)/256
#define SETUP_NB (NCHUNK + XCAST_NB + PREP_NB)

using fragAB = __attribute__((ext_vector_type(8))) short;
using fragC  = __attribute__((ext_vector_type(4))) float;

__device__ __forceinline__ unsigned short f2bf(float f) {
    unsigned int u = __float_as_uint(f);
    unsigned int r = u + 0x7FFFu + ((u >> 16) & 1u);  // RNE
    return (unsigned short)(r >> 16);
}

__device__ __forceinline__ float bflo(unsigned v) { return __uint_as_float(v << 16); }
__device__ __forceinline__ float bfhi(unsigned v) { return __uint_as_float(v & 0xffff0000u); }

// ---------------- mega_setup: bin (blocks 0..152, FIRST) | xcast | prep.
// bucket_cursor zeroed before launch (hipMemsetAsync).
// prep folds (1+eps) into Bh's L-half so the GEMM A-staging is a pure copy.
// Record = (bucket:10 | src_local:6 | dst:16). myb<NBKTP guards REQUIRED.
__global__ __launch_bounds__(256) void mega_setup(
    const float* __restrict__ X, const int* __restrict__ ei,
    const float* __restrict__ L, const float* __restrict__ W,
    const float* __restrict__ mb, const float* __restrict__ epsp,
    float* __restrict__ cb, unsigned short* __restrict__ Bh,
    unsigned short* __restrict__ Xbf,
    int* __restrict__ bucket_cursor, unsigned* __restrict__ staging) {
    __shared__ int cnt[NBKTP];
    __shared__ int base[NBKTP];
    __shared__ int gb[NBKTP];
    __shared__ int wsum[4];
    __shared__ unsigned staged[CHUNK];
    int blk = blockIdx.x;
    int t = threadIdx.x;

    if (blk >= NCHUNK) {
        int xb = blk - NCHUNK;
        if (xb < XCAST_NB) {
            // ---- xcast: X fp32 -> Xbf bf16 (compact NN x 128)
            int idx = (xb * 256 + t) * 4;
            float4 v = *(const float4*)(X + idx);
            uint2 p;
            p.x = (unsigned)f2bf(v.x) | ((unsigned)f2bf(v.y) << 16);
            p.y = (unsigned)f2bf(v.z) | ((unsigned)f2bf(v.w) << 16);
            *(uint2*)(Xbf + idx) = p;
        } else {
            // ---- prep: C = L@W, cb = L@msg_b, bf16 Bh = [(1+eps)L | C]
            int idx = (xb - XCAST_NB) * 256 + t;
            float scale = 1.0f + *epsp;
            if (idx < DIM * DIM) {
                int o = idx >> 7, g = idx & 127;
                float s = 0.f;
                for (int f = 0; f < DIM; f++) s += L[o * DIM + f] * W[f * DIM + g];
                Bh[o * 256 + 128 + g] = f2bf(s);                  // C part
                Bh[o * 256 + g] = f2bf(L[o * DIM + g] * scale);   // scaled L part
            } else if (idx < DIM * DIM + DIM) {
                int o = idx - DIM * DIM;
                float s = 0.f;
                for (int f = 0; f < DIM; f++) s += L[o * DIM + f] * mb[f];
                cb[o] = s;
            }
        }
        return;
    }

    // ---- bin @4096 (r6-r16 logic, scan via wave shuffles: 1 barrier not 16)
    int e0 = blk * CHUNK;
    int nthis = NE - e0; if (nthis > CHUNK) nthis = CHUNK;

    for (int i = t; i < NBKTP; i += 256) cnt[i] = 0;
    __syncthreads();

    unsigned pk[CHUNK / 256];
#pragma unroll
    for (int i = 0; i < CHUNK / 256; i++) {
        int e = e0 + i * 256 + t;
        if (e < NE) {
            int s = ei[e];
            int d = ei[NE + e];
            unsigned b = (unsigned)s >> 6;
            pk[i] = (b << 22) | ((unsigned)(s & 63) << 16) | (unsigned)d;
            atomicAdd(&cnt[b], 1);
        } else pk[i] = 0xFFFFFFFFu;
    }
    __syncthreads();

    int myb = t * 4;
    int s0 = 0;
    if (myb < NBKTP) s0 = cnt[myb] + cnt[myb + 1] + cnt[myb + 2] + cnt[myb + 3];
    // wave-level inclusive scan of s0 (64 lanes), then cross-wave combine
    int lane = t & 63, w = t >> 6;
    int v = s0;
#pragma unroll
    for (int off = 1; off < 64; off <<= 1) {
        int u = __shfl_up(v, off);
        if (lane >= off) v += u;
    }
    if (lane == 63) wsum[w] = v;
    __syncthreads();
    int add = 0;
#pragma unroll
    for (int i = 0; i < 4; i++)
        if (i < w) add += wsum[i];
    int run = v + add - s0;  // exclusive prefix for this thread's 4 counters
    if (myb < NBKTP) {
        for (int i = 0; i < 4; i++) {
            int b = myb + i;
            base[b] = run;
            int c = cnt[b];
            gb[b] = (b < NBKT && c > 0) ? atomicAdd(&bucket_cursor[b], c) : 0;
            run += c;
        }
    }
    __syncthreads();
    if (myb < NBKTP) {
        for (int i = 0; i < 4; i++) cnt[myb + i] = base[myb + i];  // cursor
    }
    __syncthreads();

#pragma unroll
    for (int i = 0; i < CHUNK / 256; i++) {
        if (pk[i] != 0xFFFFFFFFu) {
            unsigned b = pk[i] >> 22;
            int pos = atomicAdd(&cnt[b], 1);
            staged[pos] = pk[i];
        }
    }
    __syncthreads();

    for (int idx = t; idx < nthis; idx += 256) {
        unsigned p = staged[idx];
        unsigned b = p >> 22;
        int pos = gb[b] + (idx - base[b]);
        if (pos >= 0 && pos < CAP) staging[(size_t)b * CAP + pos] = p;
    }
}

// ---------------- fused gather + output GEMM.
// One wg (512 thr = 8 waves) per bucket of 64 src nodes:
//   phase A: LDS counting-sort of the bucket's records by src_local,
//            while coalesced-loading the bucket's own Xbf rows into the
//            X-half of the LDS A-tile As[64][256+8pad].
//   phase B: each wave gathers 8 nodes (two 32-lane halves read different
//            rows via uint2), accumulates in fp32 regs, writes the Agg-half
//            of As as bf16.  No global Aggbf, no global deg.
//   phase C: one barrier, then 64x128 output tile via MFMA 16x16x32:
//            wave (wM=wave&3, wN=wave>>2) computes rows wM*16..+15,
//            cols wN*64..+63.  A-frags from LDS; B-frags straight from
//            global Bh (64 KB, L2-resident - no LDS staging needed).
//   epilogue: out = relu(acc + hcnt[row]*cb[col] + lin_b[col]).
// LDS: rec 6K + sorted 6K + hists 0.75K + As 33.8K = 46.8 KB.
// __launch_bounds__(512,4): cap 128 VGPR -> 2 blocks/CU (16 waves).
__global__ __launch_bounds__(512, 4) void gather_gemm(
    const int* __restrict__ bucket_cursor, const unsigned* __restrict__ staging,
    const unsigned short* __restrict__ Xbf, const unsigned short* __restrict__ Bh,
    const float* __restrict__ cb, const float* __restrict__ lin_b,
    float* __restrict__ out) {
    __shared__ unsigned rec[CAP];
    __shared__ unsigned sorted_[CAP];
    __shared__ int hcnt[64];
    __shared__ int hbase[64];
    __shared__ int cur[64];
    __shared__ unsigned short As[64 * 264];  // [row][256 k + 8 pad]
    int t = threadIdx.x;
    int b = blockIdx.x;
    int cnt_b = bucket_cursor[b];
    if (cnt_b > CAP) cnt_b = CAP;

    if (t < 64) hcnt[t] = 0;
    // X-half of A-tile: 64 rows x 128 shorts = 1024 uint4, coalesced.
#pragma unroll
    for (int it = 0; it < 2; it++) {
        int idx = t + it * 512;
        int row = idx >> 4, c = idx & 15;
        int node = b * 64 + row;
        if (node >= NN) node = NN - 1;  // harmless dup; stores guarded later
        uint4 vx = *(const uint4*)(Xbf + (size_t)node * 128 + c * 8);
        *(uint4*)(As + row * 264 + c * 8) = vx;
    }
    __syncthreads();
    for (int i = t; i < cnt_b; i += 512) {
        unsigned r = staging[(size_t)b * CAP + i];
        rec[i] = r;
        atomicAdd(&hcnt[(r >> 16) & 63], 1);
    }
    __syncthreads();
    if (t < 64) {  // wave 0: 64-lane shuffle scan
        int c = hcnt[t];
        int v = c;
#pragma unroll
        for (int off = 1; off < 64; off <<= 1) {
            int u = __shfl_up(v, off);
            if (t >= off) v += u;
        }
        int ex = v - c;
        hbase[t] = ex;
        cur[t] = ex;
    }
    __syncthreads();
    for (int i = t; i < cnt_b; i += 512) {
        unsigned r = rec[i];
        int pos = atomicAdd(&cur[(r >> 16) & 63], 1);
        sorted_[pos] = r;
    }
    __syncthreads();

    // gather phase: wave w -> nodes b*64 + w*8 .. +7
    int wave = t >> 6, lane = t & 63;
    int l32 = lane & 31, half = lane >> 5;
    const uint2* __restrict__ X2 = (const uint2*)Xbf;  // 32 uint2 per row
    for (int ni = 0; ni < 8; ni++) {
        int local = wave * 8 + ni;
        int node = b * 64 + local;
        if (node >= NN) continue;
        int start = hbase[local];  // same-addr LDS read -> broadcast
        int cnt = hcnt[local];
        float a0 = 0.f, a1 = 0.f, a2 = 0.f, a3 = 0.f;
        int pairs = cnt >> 1;
        int j = 0;
        for (; j + 8 <= pairs; j += 8) {
            int d[8];
#pragma unroll
            for (int i = 0; i < 8; i++)
                d[i] = (int)(sorted_[start + 2 * (j + i) + half] & 0xFFFFu);
            uint2 v[8];
#pragma unroll
            for (int i = 0; i < 8; i++) v[i] = X2[(size_t)d[i] * 32 + l32];
#pragma unroll
            for (int i = 0; i < 8; i++) {
                a0 += bflo(v[i].x);
                a1 += bfhi(v[i].x);
                a2 += bflo(v[i].y);
                a3 += bfhi(v[i].y);
            }
        }
        for (; j < pairs; j++) {
            int d = (int)(sorted_[start + 2 * j + half] & 0xFFFFu);
            uint2 v = X2[(size_t)d * 32 + l32];
            a0 += bflo(v.x);
            a1 += bfhi(v.x);
            a2 += bflo(v.y);
            a3 += bfhi(v.y);
        }
        if ((cnt & 1) && half == 0) {
            int d = (int)(sorted_[start + cnt - 1] & 0xFFFFu);
            uint2 v = X2[(size_t)d * 32 + l32];
            a0 += bflo(v.x);
            a1 += bfhi(v.x);
            a2 += bflo(v.y);
            a3 += bfhi(v.y);
        }
        a0 += __shfl_xor(a0, 32);
        a1 += __shfl_xor(a1, 32);
        a2 += __shfl_xor(a2, 32);
        a3 += __shfl_xor(a3, 32);
        if (half == 0) {
            uint2 p;
            p.x = (unsigned)f2bf(a0) | ((unsigned)f2bf(a1) << 16);
            p.y = (unsigned)f2bf(a2) | ((unsigned)f2bf(a3) << 16);
            *(uint2*)(As + local * 264 + 128 + l32 * 4) = p;  // Agg-half
        }
    }
    __syncthreads();

    // MFMA phase: out tile 64x128.  wave -> rows (wave&3)*16, cols (wave>>2)*64
    int m16 = lane & 15;
    int quad = lane >> 4;
    int waveM = (wave & 3) * 16;
    int waveN = (wave >> 2) * 64;

    fragC acc[4];
#pragma unroll
    for (int j = 0; j < 4; j++) acc[j] = (fragC){0.f, 0.f, 0.f, 0.f};

#pragma unroll
    for (int kc = 0; kc < 8; kc++) {
        fragAB a = *(const fragAB*)(As + (waveM + m16) * 264 + kc * 32 + quad * 8);
#pragma unroll
        for (int j = 0; j < 4; j++) {
            fragAB bf = *(const fragAB*)(Bh + (size_t)(waveN + j * 16 + m16) * 256 + kc * 32 + quad * 8);
            acc[j] = __builtin_amdgcn_mfma_f32_16x16x32_bf16(a, bf, acc[j], 0, 0, 0);
        }
    }

#pragma unroll
    for (int j = 0; j < 4; j++) {
        int col = waveN + j * 16 + m16;
        float cbc = cb[col];
        float lbc = lin_b[col];
        int lr = waveM + quad * 4;
#pragma unroll
        for (int r = 0; r < 4; r++) {
            int row = lr + r;
            int node = b * 64 + row;
            if (node < NN) {
                float dg = (float)hcnt[row];
                float v = acc[j][r] + dg * cbc + lbc;
                out[(size_t)node * 128 + col] = fmaxf(v, 0.f);
            }
        }
    }
}

extern "C" void kernel_launch(void* const* d_in, const int* in_sizes, int n_in,
                              void* d_out, int out_size, void* d_ws, size_t ws_size,
                              hipStream_t stream) {
    const float* X = (const float*)d_in[0];
    const int* ei = (const int*)d_in[1];
    const float* epsp = (const float*)d_in[2];
    const float* msg_w = (const float*)d_in[3];
    const float* msg_b = (const float*)d_in[4];
    const float* lin_w = (const float*)d_in[5];
    const float* lin_b = (const float*)d_in[6];
    float* out = (float*)d_out;

    // workspace (~18 MB)
    int* bucket_cursor = (int*)d_ws;                       // 800
    unsigned* staging = (unsigned*)(bucket_cursor + 800);  // NBKT*CAP = 4.8 MB
    float* cb = (float*)(staging + (size_t)NBKT * CAP);    // DIM floats
    unsigned short* Bh = (unsigned short*)(cb + DIM);      // 128*256 bf16
    unsigned short* Xbf = Bh + 128 * 256;                  // NN*128 bf16 = 12.8 MB

    hipMemsetAsync(bucket_cursor, 0, NBKTP * sizeof(int), stream);

    mega_setup<<<SETUP_NB, 256, 0, stream>>>(X, ei, lin_w, msg_w, msg_b, epsp, cb, Bh, Xbf,
                                             bucket_cursor, staging);
    gather_gemm<<<NBKT, 512, 0, stream>>>(bucket_cursor, staging, Xbf, Bh, cb, lin_b, out);
}

// Round 2
// 158.988 us; speedup vs baseline: 1.1416x; 1.1416x over previous
//
#include <hip/hip_runtime.h>
#include <hip/hip_bf16.h>

#define NN 50000
#define NE 625000
#define DIM 128

#define NBKT 782     // ceil(50000/64) buckets of 64 src nodes
#define NBKTP 784    // padded to multiple of 4
#define CAP 1024     // per-bucket capacity (mean 800, sd ~28 -> +8 sigma)
#define CHUNK 4096   // edges per bin block (153 bin blocks)
#define NCHUNK ((NE + CHUNK - 1) / CHUNK)  // 153

// mega_setup grid partition: bin FIRST (long blocks overlap xcast stream)
#define XCAST_NB 6250              // NN*DIM/4/256
#define PREP_NB 65                 // (DIM*DIM+DIM+255)/256
#define SETUP_NB (NCHUNK + XCAST_NB + PREP_NB)

using fragAB = __attribute__((ext_vector_type(8))) short;
using fragC  = __attribute__((ext_vector_type(4))) float;

__device__ __forceinline__ unsigned short f2bf(float f) {
    unsigned int u = __float_as_uint(f);
    unsigned int r = u + 0x7FFFu + ((u >> 16) & 1u);  // RNE
    return (unsigned short)(r >> 16);
}

__device__ __forceinline__ float bflo(unsigned v) { return __uint_as_float(v << 16); }
__device__ __forceinline__ float bfhi(unsigned v) { return __uint_as_float(v & 0xffff0000u); }

// ---------------- mega_setup: bin (blocks 0..152, FIRST) | xcast | prep.
// bucket_cursor zeroed before launch (hipMemsetAsync).
// prep folds (1+eps) into Bh's L-half so the GEMM A-staging is a pure copy.
// Record = (bucket:10 | src_local:6 | dst:16). myb<NBKTP guards REQUIRED.
__global__ __launch_bounds__(256) void mega_setup(
    const float* __restrict__ X, const int* __restrict__ ei,
    const float* __restrict__ L, const float* __restrict__ W,
    const float* __restrict__ mb, const float* __restrict__ epsp,
    float* __restrict__ cb, unsigned short* __restrict__ Bh,
    unsigned short* __restrict__ Xbf,
    int* __restrict__ bucket_cursor, unsigned* __restrict__ staging) {
    __shared__ int cnt[NBKTP];
    __shared__ int base[NBKTP];
    __shared__ int gb[NBKTP];
    __shared__ int wsum[4];
    __shared__ unsigned staged[CHUNK];
    int blk = blockIdx.x;
    int t = threadIdx.x;

    if (blk >= NCHUNK) {
        int xb = blk - NCHUNK;
        if (xb < XCAST_NB) {
            // ---- xcast: X fp32 -> Xbf bf16 (compact NN x 128)
            int idx = (xb * 256 + t) * 4;
            float4 v = *(const float4*)(X + idx);
            uint2 p;
            p.x = (unsigned)f2bf(v.x) | ((unsigned)f2bf(v.y) << 16);
            p.y = (unsigned)f2bf(v.z) | ((unsigned)f2bf(v.w) << 16);
            *(uint2*)(Xbf + idx) = p;
        } else {
            // ---- prep: C = L@W, cb = L@msg_b, bf16 Bh = [(1+eps)L | C]
            int idx = (xb - XCAST_NB) * 256 + t;
            float scale = 1.0f + *epsp;
            if (idx < DIM * DIM) {
                int o = idx >> 7, g = idx & 127;
                float s = 0.f;
                for (int f = 0; f < DIM; f++) s += L[o * DIM + f] * W[f * DIM + g];
                Bh[o * 256 + 128 + g] = f2bf(s);                  // C part
                Bh[o * 256 + g] = f2bf(L[o * DIM + g] * scale);   // scaled L part
            } else if (idx < DIM * DIM + DIM) {
                int o = idx - DIM * DIM;
                float s = 0.f;
                for (int f = 0; f < DIM; f++) s += L[o * DIM + f] * mb[f];
                cb[o] = s;
            }
        }
        return;
    }

    // ---- bin @4096 (r6-r16 logic, scan via wave shuffles: 1 barrier not 16)
    int e0 = blk * CHUNK;
    int nthis = NE - e0; if (nthis > CHUNK) nthis = CHUNK;

    for (int i = t; i < NBKTP; i += 256) cnt[i] = 0;
    __syncthreads();

    unsigned pk[CHUNK / 256];
#pragma unroll
    for (int i = 0; i < CHUNK / 256; i++) {
        int e = e0 + i * 256 + t;
        if (e < NE) {
            int s = ei[e];
            int d = ei[NE + e];
            unsigned b = (unsigned)s >> 6;
            pk[i] = (b << 22) | ((unsigned)(s & 63) << 16) | (unsigned)d;
            atomicAdd(&cnt[b], 1);
        } else pk[i] = 0xFFFFFFFFu;
    }
    __syncthreads();

    int myb = t * 4;
    int s0 = 0;
    if (myb < NBKTP) s0 = cnt[myb] + cnt[myb + 1] + cnt[myb + 2] + cnt[myb + 3];
    // wave-level inclusive scan of s0 (64 lanes), then cross-wave combine
    int lane = t & 63, w = t >> 6;
    int v = s0;
#pragma unroll
    for (int off = 1; off < 64; off <<= 1) {
        int u = __shfl_up(v, off);
        if (lane >= off) v += u;
    }
    if (lane == 63) wsum[w] = v;
    __syncthreads();
    int add = 0;
#pragma unroll
    for (int i = 0; i < 4; i++)
        if (i < w) add += wsum[i];
    int run = v + add - s0;  // exclusive prefix for this thread's 4 counters
    if (myb < NBKTP) {
        for (int i = 0; i < 4; i++) {
            int b = myb + i;
            base[b] = run;
            int c = cnt[b];
            gb[b] = (b < NBKT && c > 0) ? atomicAdd(&bucket_cursor[b], c) : 0;
            run += c;
        }
    }
    __syncthreads();
    if (myb < NBKTP) {
        for (int i = 0; i < 4; i++) cnt[myb + i] = base[myb + i];  // cursor
    }
    __syncthreads();

#pragma unroll
    for (int i = 0; i < CHUNK / 256; i++) {
        if (pk[i] != 0xFFFFFFFFu) {
            unsigned b = pk[i] >> 22;
            int pos = atomicAdd(&cnt[b], 1);
            staged[pos] = pk[i];
        }
    }
    __syncthreads();

    for (int idx = t; idx < nthis; idx += 256) {
        unsigned p = staged[idx];
        unsigned b = p >> 22;
        int pos = gb[b] + (idx - base[b]);
        if (pos >= 0 && pos < CAP) staging[(size_t)b * CAP + pos] = p;
    }
}

// ---------------- fused gather + output GEMM.
// One wg (512 thr = 8 waves) per bucket of 64 src nodes:
//   phase A: records staged in REGISTERS (<=2/thread, CAP=1024), LDS
//            counting-sort by src_local; bucket's own Xbf rows issued into
//            regs at kernel start, written to the X-half of As after scatter.
//   phase B: gather with quarter-wave rows: each 16-lane quarter reads one
//            full 256B row via uint4, 4 quarters = 4 edges of the same node
//            in flight, 2-deep unrolled -> 8 rows outstanding per wave.
//            Cross-quarter reduce: 2 shfl_xor rounds. Agg written as bf16
//            into the Agg-half of As. No global Aggbf, no global deg.
//   phase C: 64x128 output tile via MFMA 16x16x32; A-frags from LDS,
//            B-frags straight from global Bh (64 KB, L2-resident).
//   epilogue: out = relu(acc + hcnt[row]*cb[col] + lin_b[col]).
// LDS: sorted 4K + hists 0.75K + As 33.8K = 38.7 KB -> 4 blocks/CU.
// __launch_bounds__(512,8): cap 64 VGPR -> 32 waves/CU (100% cap).
__global__ __launch_bounds__(512, 8) void gather_gemm(
    const int* __restrict__ bucket_cursor, const unsigned* __restrict__ staging,
    const unsigned short* __restrict__ Xbf, const unsigned short* __restrict__ Bh,
    const float* __restrict__ cb, const float* __restrict__ lin_b,
    float* __restrict__ out) {
    __shared__ unsigned sorted_[CAP];
    __shared__ int hcnt[64];
    __shared__ int hbase[64];
    __shared__ int cur[64];
    __shared__ unsigned short As[64 * 264];  // [row][256 k + 8 pad]
    int t = threadIdx.x;
    int b = blockIdx.x;
    int cnt_b = bucket_cursor[b];
    if (cnt_b > CAP) cnt_b = CAP;

    // issue X-half loads early (2 uint4/thread); written to LDS post-scatter
    int xrow0 = t >> 4, xc0 = t & 15;           // rows 0..31
    int xrow1 = xrow0 + 32;                      // rows 32..63
    int xnode0 = b * 64 + xrow0; if (xnode0 >= NN) xnode0 = NN - 1;
    int xnode1 = b * 64 + xrow1; if (xnode1 >= NN) xnode1 = NN - 1;
    uint4 xv0 = *(const uint4*)(Xbf + (size_t)xnode0 * 128 + xc0 * 8);
    uint4 xv1 = *(const uint4*)(Xbf + (size_t)xnode1 * 128 + xc0 * 8);

    // records in regs: <=2 per thread
    unsigned r0 = 0xFFFFFFFFu, r1 = 0xFFFFFFFFu;
    if (t < cnt_b) r0 = staging[(size_t)b * CAP + t];
    if (t + 512 < cnt_b) r1 = staging[(size_t)b * CAP + t + 512];

    if (t < 64) hcnt[t] = 0;
    __syncthreads();
    if (r0 != 0xFFFFFFFFu) atomicAdd(&hcnt[(r0 >> 16) & 63], 1);
    if (r1 != 0xFFFFFFFFu) atomicAdd(&hcnt[(r1 >> 16) & 63], 1);
    __syncthreads();
    if (t < 64) {  // wave 0: 64-lane shuffle scan
        int c = hcnt[t];
        int v = c;
#pragma unroll
        for (int off = 1; off < 64; off <<= 1) {
            int u = __shfl_up(v, off);
            if (t >= off) v += u;
        }
        int ex = v - c;
        hbase[t] = ex;
        cur[t] = ex;
    }
    __syncthreads();
    if (r0 != 0xFFFFFFFFu) {
        int pos = atomicAdd(&cur[(r0 >> 16) & 63], 1);
        sorted_[pos] = r0;
    }
    if (r1 != 0xFFFFFFFFu) {
        int pos = atomicAdd(&cur[(r1 >> 16) & 63], 1);
        sorted_[pos] = r1;
    }
    // write X-half of As (no barrier needed until MFMA phase)
    *(uint4*)(As + xrow0 * 264 + xc0 * 8) = xv0;
    *(uint4*)(As + xrow1 * 264 + xc0 * 8) = xv1;
    __syncthreads();

    // gather phase: wave w -> nodes b*64 + w*8 .. +7.
    // quarter q (16 lanes) reads full rows (uint4/lane), edges q, q+4, ...
    int wave = t >> 6, lane = t & 63;
    int q = lane >> 4, l16 = lane & 15;
    const uint4* __restrict__ X4 = (const uint4*)Xbf;  // 16 uint4 per row
    for (int ni = 0; ni < 8; ni++) {
        int local = wave * 8 + ni;
        int node = b * 64 + local;
        if (node >= NN) continue;
        int start = hbase[local];  // same-addr LDS read -> broadcast
        int cnt = hcnt[local];
        float a0 = 0.f, a1 = 0.f, a2 = 0.f, a3 = 0.f;
        float a4 = 0.f, a5 = 0.f, a6 = 0.f, a7 = 0.f;
        int j = q;
        for (; j + 4 < cnt; j += 8) {  // 2-deep: 8 rows in flight per wave
            int d0 = (int)(sorted_[start + j] & 0xFFFFu);
            int d1 = (int)(sorted_[start + j + 4] & 0xFFFFu);
            uint4 v0 = X4[(size_t)d0 * 16 + l16];
            uint4 v1 = X4[(size_t)d1 * 16 + l16];
            a0 += bflo(v0.x); a1 += bfhi(v0.x);
            a2 += bflo(v0.y); a3 += bfhi(v0.y);
            a4 += bflo(v0.z); a5 += bfhi(v0.z);
            a6 += bflo(v0.w); a7 += bfhi(v0.w);
            a0 += bflo(v1.x); a1 += bfhi(v1.x);
            a2 += bflo(v1.y); a3 += bfhi(v1.y);
            a4 += bflo(v1.z); a5 += bfhi(v1.z);
            a6 += bflo(v1.w); a7 += bfhi(v1.w);
        }
        if (j < cnt) {
            int d0 = (int)(sorted_[start + j] & 0xFFFFu);
            uint4 v0 = X4[(size_t)d0 * 16 + l16];
            a0 += bflo(v0.x); a1 += bfhi(v0.x);
            a2 += bflo(v0.y); a3 += bfhi(v0.y);
            a4 += bflo(v0.z); a5 += bfhi(v0.z);
            a6 += bflo(v0.w); a7 += bfhi(v0.w);
        }
        // reduce across quarters (xor 16, then 32)
        a0 += __shfl_xor(a0, 16); a1 += __shfl_xor(a1, 16);
        a2 += __shfl_xor(a2, 16); a3 += __shfl_xor(a3, 16);
        a4 += __shfl_xor(a4, 16); a5 += __shfl_xor(a5, 16);
        a6 += __shfl_xor(a6, 16); a7 += __shfl_xor(a7, 16);
        a0 += __shfl_xor(a0, 32); a1 += __shfl_xor(a1, 32);
        a2 += __shfl_xor(a2, 32); a3 += __shfl_xor(a3, 32);
        a4 += __shfl_xor(a4, 32); a5 += __shfl_xor(a5, 32);
        a6 += __shfl_xor(a6, 32); a7 += __shfl_xor(a7, 32);
        if (q == 0) {
            uint4 p;
            p.x = (unsigned)f2bf(a0) | ((unsigned)f2bf(a1) << 16);
            p.y = (unsigned)f2bf(a2) | ((unsigned)f2bf(a3) << 16);
            p.z = (unsigned)f2bf(a4) | ((unsigned)f2bf(a5) << 16);
            p.w = (unsigned)f2bf(a6) | ((unsigned)f2bf(a7) << 16);
            *(uint4*)(As + local * 264 + 128 + l16 * 8) = p;  // Agg-half
        }
    }
    __syncthreads();

    // MFMA phase: out tile 64x128.  wave -> rows (wave&3)*16, cols (wave>>2)*64
    int m16 = lane & 15;
    int quad = lane >> 4;
    int waveM = (wave & 3) * 16;
    int waveN = (wave >> 2) * 64;

    fragC acc[4];
#pragma unroll
    for (int j = 0; j < 4; j++) acc[j] = (fragC){0.f, 0.f, 0.f, 0.f};

#pragma unroll
    for (int kc = 0; kc < 8; kc++) {
        fragAB a = *(const fragAB*)(As + (waveM + m16) * 264 + kc * 32 + quad * 8);
#pragma unroll
        for (int j = 0; j < 4; j++) {
            fragAB bf = *(const fragAB*)(Bh + (size_t)(waveN + j * 16 + m16) * 256 + kc * 32 + quad * 8);
            acc[j] = __builtin_amdgcn_mfma_f32_16x16x32_bf16(a, bf, acc[j], 0, 0, 0);
        }
    }

#pragma unroll
    for (int j = 0; j < 4; j++) {
        int col = waveN + j * 16 + m16;
        float cbc = cb[col];
        float lbc = lin_b[col];
        int lr = waveM + quad * 4;
#pragma unroll
        for (int r = 0; r < 4; r++) {
            int row = lr + r;
            int node = b * 64 + row;
            if (node < NN) {
                float dg = (float)hcnt[row];
                float v = acc[j][r] + dg * cbc + lbc;
                out[(size_t)node * 128 + col] = fmaxf(v, 0.f);
            }
        }
    }
}

extern "C" void kernel_launch(void* const* d_in, const int* in_sizes, int n_in,
                              void* d_out, int out_size, void* d_ws, size_t ws_size,
                              hipStream_t stream) {
    const float* X = (const float*)d_in[0];
    const int* ei = (const int*)d_in[1];
    const float* epsp = (const float*)d_in[2];
    const float* msg_w = (const float*)d_in[3];
    const float* msg_b = (const float*)d_in[4];
    const float* lin_w = (const float*)d_in[5];
    const float* lin_b = (const float*)d_in[6];
    float* out = (float*)d_out;

    // workspace (~16 MB)
    int* bucket_cursor = (int*)d_ws;                       // 800
    unsigned* staging = (unsigned*)(bucket_cursor + 800);  // NBKT*CAP = 3.2 MB
    float* cb = (float*)(staging + (size_t)NBKT * CAP);    // DIM floats
    unsigned short* Bh = (unsigned short*)(cb + DIM);      // 128*256 bf16
    unsigned short* Xbf = Bh + 128 * 256;                  // NN*128 bf16 = 12.8 MB

    hipMemsetAsync(bucket_cursor, 0, NBKTP * sizeof(int), stream);

    mega_setup<<<SETUP_NB, 256, 0, stream>>>(X, ei, lin_w, msg_w, msg_b, epsp, cb, Bh, Xbf,
                                             bucket_cursor, staging);
    gather_gemm<<<NBKT, 512, 0, stream>>>(bucket_cursor, staging, Xbf, Bh, cb, lin_b, out);
}